// Round 1
// baseline (1309.769 us; speedup 1.0000x reference)
//
#include <hip/hip_runtime.h>
#include <hip/hip_bf16.h>

#define Bn 4
#define Nn 40
#define Fn 128
#define NCUBE (Nn*Nn*Nn)        // 64000
#define R 8                      // rows per block in main kernel
#define ABLOCKS 250              // blocks per batch in sumexp kernel

// ---------------------------------------------------------------------------
// Kernel A: per-(batch,channel) sum of exp(x_embed) over VALID hyperedges.
// Valid = (i<j<k) && mask[i]&&mask[j]&&mask[k]. Only ~15% of rows are valid,
// so we check first and skip. Block = 128 threads (one per channel), one row
// at a time; block-local accumulation, one atomicAdd per thread at the end.
// ---------------------------------------------------------------------------
__global__ __launch_bounds__(128)
void sumexp_kernel(const float* __restrict__ x,
                   const unsigned char* __restrict__ mask,
                   const float* __restrict__ Wi1, const float* __restrict__ bi1,
                   const float* __restrict__ Wi2, const float* __restrict__ bi2,
                   float* __restrict__ sums)
{
    const int t = threadIdx.x;
    const int b = blockIdx.x / ABLOCKS;
    const int g = blockIdx.x % ABLOCKS;
    const int rows_per_block = NCUBE / ABLOCKS;   // 256

    __shared__ __align__(16) float xs[Fn];
    __shared__ __align__(16) float h1s[Fn];

    const float b1 = bi1[t];
    const float b2 = bi2[t];
    float acc_sum = 0.0f;
    bool any = false;

    for (int r = 0; r < rows_per_block; ++r) {
        const int e = g * rows_per_block + r;       // row index within batch
        const int k  = e % Nn;
        const int ij = e / Nn;
        const int j  = ij % Nn;
        const int i  = ij / Nn;
        // uniform across the block
        const bool valid = (i < j) && (j < k) &&
                           mask[b*Nn + i] && mask[b*Nn + j] && mask[b*Nn + k];
        if (!valid) continue;
        any = true;

        __syncthreads();                            // protect xs/h1s reuse
        xs[t] = x[((long)(b*NCUBE + e))*Fn + t];
        __syncthreads();

        float acc = b1;
        #pragma unroll 4
        for (int f = 0; f < Fn; ++f) acc = fmaf(xs[f], Wi1[f*Fn + t], acc);
        h1s[t] = fmaxf(acc, 0.0f);
        __syncthreads();

        float acc2 = b2;
        #pragma unroll 4
        for (int f = 0; f < Fn; ++f) acc2 = fmaf(h1s[f], Wi2[f*Fn + t], acc2);

        acc_sum += __expf(acc2);
    }
    if (any) atomicAdd(&sums[b*Fn + t], acc_sum);
}

// ---------------------------------------------------------------------------
// Kernel B: full fused pipeline for ALL rows (invalid rows still produce
// output through the h=[0, xf] path). 128 threads, R=8 rows per block.
// Thread t owns channel t (and 256-channel stage columns t and t+128).
// Weight access pattern: f-outer, coalesced column loads (L2-resident),
// amortized over 8 rows.
// ---------------------------------------------------------------------------
__global__ __launch_bounds__(128)
void main_kernel(const float* __restrict__ x,
                 const unsigned char* __restrict__ mask,
                 const float* __restrict__ Wi1, const float* __restrict__ bi1,
                 const float* __restrict__ Wi2, const float* __restrict__ bi2,
                 const float* __restrict__ We,
                 const float* __restrict__ Wo1, const float* __restrict__ bo1,
                 const float* __restrict__ Wo2, const float* __restrict__ bo2,
                 const float* __restrict__ sums,
                 float* __restrict__ out)
{
    const int t = threadIdx.x;
    const int blocks_per_batch = NCUBE / R;          // 8000
    const int b = blockIdx.x / blocks_per_batch;
    const int e_in_b = (blockIdx.x % blocks_per_batch) * R;
    const long e0 = (long)b * NCUBE + e_in_b;

    __shared__ __align__(16) float xs [R][Fn];
    __shared__ __align__(16) float h1s[R][Fn];
    __shared__ __align__(16) float xfs[R][Fn];
    __shared__ __align__(16) float hs [R][2*Fn];
    __shared__ float wred[2][R];

    // validity per row (uniform across threads)
    bool valid[R];
    #pragma unroll
    for (int r = 0; r < R; ++r) {
        const int e  = e_in_b + r;
        const int k  = e % Nn;
        const int ij = e / Nn;
        const int j  = ij % Nn;
        const int i  = ij / Nn;
        valid[r] = (i < j) && (j < k) &&
                   mask[b*Nn + i] && mask[b*Nn + j] && mask[b*Nn + k];
    }

    // load x rows (coalesced)
    #pragma unroll
    for (int r = 0; r < R; ++r) xs[r][t] = x[(e0 + r)*Fn + t];
    __syncthreads();

    // ---- stage 1: h1 = relu(x @ Wi1 + bi1) ----
    float acc[R];
    {
        const float b1 = bi1[t];
        #pragma unroll
        for (int r = 0; r < R; ++r) acc[r] = b1;
        for (int f = 0; f < Fn; f += 4) {
            const float w0 = Wi1[(f+0)*Fn + t];
            const float w1 = Wi1[(f+1)*Fn + t];
            const float w2 = Wi1[(f+2)*Fn + t];
            const float w3 = Wi1[(f+3)*Fn + t];
            #pragma unroll
            for (int r = 0; r < R; ++r) {
                const float4 xv = *(const float4*)&xs[r][f];
                acc[r] = fmaf(xv.x, w0, fmaf(xv.y, w1, fmaf(xv.z, w2, fmaf(xv.w, w3, acc[r]))));
            }
        }
        #pragma unroll
        for (int r = 0; r < R; ++r) h1s[r][t] = fmaxf(acc[r], 0.0f);
    }
    __syncthreads();

    // ---- stage 2: xf = h1 @ Wi2 + bi2 ----
    float xf[R];
    {
        const float b2 = bi2[t];
        #pragma unroll
        for (int r = 0; r < R; ++r) acc[r] = b2;
        for (int f = 0; f < Fn; f += 4) {
            const float w0 = Wi2[(f+0)*Fn + t];
            const float w1 = Wi2[(f+1)*Fn + t];
            const float w2 = Wi2[(f+2)*Fn + t];
            const float w3 = Wi2[(f+3)*Fn + t];
            #pragma unroll
            for (int r = 0; r < R; ++r) {
                const float4 hv = *(const float4*)&h1s[r][f];
                acc[r] = fmaf(hv.x, w0, fmaf(hv.y, w1, fmaf(hv.z, w2, fmaf(hv.w, w3, acc[r]))));
            }
        }
        #pragma unroll
        for (int r = 0; r < R; ++r) { xf[r] = acc[r]; xfs[r][t] = acc[r]; }
    }
    __syncthreads();

    // ---- stage 3: xi = relu(xf @ We) ----
    float xi[R];
    {
        #pragma unroll
        for (int r = 0; r < R; ++r) acc[r] = 0.0f;
        for (int f = 0; f < Fn; f += 4) {
            const float w0 = We[(f+0)*Fn + t];
            const float w1 = We[(f+1)*Fn + t];
            const float w2 = We[(f+2)*Fn + t];
            const float w3 = We[(f+3)*Fn + t];
            #pragma unroll
            for (int r = 0; r < R; ++r) {
                const float4 fv = *(const float4*)&xfs[r][f];
                acc[r] = fmaf(fv.x, w0, fmaf(fv.y, w1, fmaf(fv.z, w2, fmaf(fv.w, w3, acc[r]))));
            }
        }
        #pragma unroll
        for (int r = 0; r < R; ++r) xi[r] = fmaxf(acc[r], 0.0f);
    }

    // ---- softmax weight + build h = [a * xi, xf] ----
    {
        const float rinv = 1.0f / sums[b*Fn + t];
        #pragma unroll
        for (int r = 0; r < R; ++r) {
            const float a = valid[r] ? __expf(xf[r]) * rinv : 0.0f;
            hs[r][t]      = a * xi[r];
            hs[r][Fn + t] = xf[r];
        }
    }
    __syncthreads();

    // ---- stage 4: g = relu(h @ Wo1 + bo1), thread t owns cols t and t+128 ----
    float accA[R], accB[R];
    {
        const float ba = bo1[t];
        const float bb = bo1[t + Fn];
        #pragma unroll
        for (int r = 0; r < R; ++r) { accA[r] = ba; accB[r] = bb; }
        for (int v = 0; v < 2*Fn; v += 4) {
            const float wa0 = Wo1[(v+0)*2*Fn + t];
            const float wa1 = Wo1[(v+1)*2*Fn + t];
            const float wa2 = Wo1[(v+2)*2*Fn + t];
            const float wa3 = Wo1[(v+3)*2*Fn + t];
            const float wb0 = Wo1[(v+0)*2*Fn + t + Fn];
            const float wb1 = Wo1[(v+1)*2*Fn + t + Fn];
            const float wb2 = Wo1[(v+2)*2*Fn + t + Fn];
            const float wb3 = Wo1[(v+3)*2*Fn + t + Fn];
            #pragma unroll
            for (int r = 0; r < R; ++r) {
                const float4 hv = *(const float4*)&hs[r][v];
                accA[r] = fmaf(hv.x, wa0, fmaf(hv.y, wa1, fmaf(hv.z, wa2, fmaf(hv.w, wa3, accA[r]))));
                accB[r] = fmaf(hv.x, wb0, fmaf(hv.y, wb1, fmaf(hv.z, wb2, fmaf(hv.w, wb3, accB[r]))));
            }
        }
    }

    // ---- stage 5: out = g @ Wo2 + bo2, reduce 256 -> 1 per row ----
    {
        const float wo2a = Wo2[t];
        const float wo2b = Wo2[t + Fn];
        float partial[R];
        #pragma unroll
        for (int r = 0; r < R; ++r)
            partial[r] = fmaxf(accA[r], 0.0f) * wo2a + fmaxf(accB[r], 0.0f) * wo2b;

        #pragma unroll
        for (int r = 0; r < R; ++r)
            for (int off = 32; off > 0; off >>= 1)
                partial[r] += __shfl_down(partial[r], off);

        const int wave = t >> 6, lane = t & 63;
        if (lane == 0) {
            #pragma unroll
            for (int r = 0; r < R; ++r) wred[wave][r] = partial[r];
        }
        __syncthreads();
        if (t < R) out[e0 + t] = wred[0][t] + wred[1][t] + bo2[0];
    }
}

extern "C" void kernel_launch(void* const* d_in, const int* in_sizes, int n_in,
                              void* d_out, int out_size, void* d_ws, size_t ws_size,
                              hipStream_t stream) {
    const float*         x    = (const float*)d_in[0];
    const unsigned char* mask = (const unsigned char*)d_in[1];   // np.bool_ = 1 byte
    const float* Wi1 = (const float*)d_in[2];
    const float* bi1 = (const float*)d_in[3];
    const float* Wi2 = (const float*)d_in[4];
    const float* bi2 = (const float*)d_in[5];
    const float* We  = (const float*)d_in[6];
    const float* Wo1 = (const float*)d_in[7];
    const float* bo1 = (const float*)d_in[8];
    const float* Wo2 = (const float*)d_in[9];
    const float* bo2 = (const float*)d_in[10];
    float* out  = (float*)d_out;
    float* sums = (float*)d_ws;   // Bn*Fn = 512 floats

    hipMemsetAsync(d_ws, 0, Bn*Fn*sizeof(float), stream);
    sumexp_kernel<<<Bn*ABLOCKS, 128, 0, stream>>>(x, mask, Wi1, bi1, Wi2, bi2, sums);
    main_kernel<<<(Bn*NCUBE)/R, 128, 0, stream>>>(x, mask, Wi1, bi1, Wi2, bi2,
                                                  We, Wo1, bo1, Wo2, bo2, sums, out);
}